// Round 7
// baseline (313.804 us; speedup 1.0000x reference)
//
#include <hip/hip_runtime.h>
#include <hip/hip_bf16.h>

typedef short s8v  __attribute__((ext_vector_type(8)));
typedef float f4v  __attribute__((ext_vector_type(4)));
typedef float f16v __attribute__((ext_vector_type(16)));

#define MFMA32 __builtin_amdgcn_mfma_f32_32x32x16_bf16

// LDS element offsets (16-bit elements). Weights only; activations in regs.
constexpr int OFF_W0T  = 0;      // [64][40]  Ws0^T, k<32
constexpr int OFF_W1T  = 2560;   // [64][72]  Ws1^T
constexpr int OFF_W2T  = 7168;   // [32][72]  Ws2^T, rows>=16 zero
constexpr int OFF_WC0T = 9472;   // [64][72]  Wc0^T: k<32=d, k=32 zero,
                                 //           k in [33,48)=geo shifted, k>=48 zero
constexpr int OFF_WC1T = 14080;  // [64][72]
constexpr int OFF_WC2T = 18688;  // [64][72]
constexpr int OFF_WC3T = 23296;  // [32][72]  rows>=3 zero
constexpr int SMEM_EL  = 25600;  // 51200 B

static __device__ __forceinline__ short bf2s(__hip_bfloat16 h) {
    union { __hip_bfloat16 b; short s; } u; u.b = h; return u.s;
}

__global__ __launch_bounds__(512, 4)
void rf_fused(const void* __restrict__ xv,
              const void* __restrict__ dv,
              const void* __restrict__ Ws0,
              const void* __restrict__ Ws1,
              const void* __restrict__ Ws2,
              const void* __restrict__ Wc0,
              const void* __restrict__ Wc1,
              const void* __restrict__ Wc2,
              const void* __restrict__ Wc3,
              void* __restrict__ outp,
              int npts)
{
    __shared__ __align__(16) short smem[SMEM_EL];
    __shared__ int cls_cnt;
    const int t = threadIdx.x;

    // ---- input dtype self-detection ----
    if (t == 0) cls_cnt = 0;
    __syncthreads();
    {
        unsigned short w = ((const unsigned short*)xv)[2 * t];
        int e = (w >> 7) & 0xFF;
        if (e >= 110 && e <= 140) atomicAdd(&cls_cnt, 1);
    }
    __syncthreads();
    const bool isbf = (cls_cnt >= 256);

    auto ldw = [&](const void* p, int idx) -> short {
        if (isbf) return ((const short*)p)[idx];
        return bf2s(__float2bfloat16(((const float*)p)[idx]));
    };

    // ---- stage weights transposed: sW[n][k] = W[k][n] ----
    for (int i = t; i < 2048; i += 512) { int k = i >> 6, n = i & 63; smem[OFF_W0T + n*40 + k] = ldw(Ws0, i); }
    for (int i = t; i < 4096; i += 512) { int k = i >> 6, n = i & 63; smem[OFF_W1T + n*72 + k] = ldw(Ws1, i); }
    // Ws2^T padded to 32 rows (rows 16..31 zero)
    for (int i = t; i < 2048; i += 512) {
        int n = i >> 6, k = i & 63;
        smem[OFF_W2T + n*72 + k] = (n < 16) ? ldw(Ws2, k*16 + n) : (short)0;
    }
    // Wc0: rows 0..31 at k=row (d); rows 32..46 at k=row+1 (geo, shifted);
    // k=32 and k>=48 zero. Absorbs the geo feature shift.
    for (int i = t; i < 4096; i += 512) {
        int n = i >> 6, k = i & 63;
        short v = 0;
        if (k < 32)                 v = ldw(Wc0, k*64 + n);
        else if (k >= 33 && k < 48) v = ldw(Wc0, (k-1)*64 + n);
        smem[OFF_WC0T + n*72 + k] = v;
    }
    for (int i = t; i < 4096; i += 512) { int k = i >> 6, n = i & 63; smem[OFF_WC1T + n*72 + k] = ldw(Wc1, i); }
    for (int i = t; i < 4096; i += 512) { int k = i >> 6, n = i & 63; smem[OFF_WC2T + n*72 + k] = ldw(Wc2, i); }
    // Wc3^T padded to 32 rows (rows 3..31 zero)
    for (int i = t; i < 2048; i += 512) {
        int n = i >> 6, k = i & 63;
        smem[OFF_WC3T + n*72 + k] = (n < 3) ? ldw(Wc3, k*3 + n) : (short)0;
    }
    __syncthreads();

    const int lane = t & 63;
    const int wv   = t >> 6;
    const int l5   = lane & 31;   // point (B/D col) or out-feature (A row)
    const int hi   = lane >> 5;   // k-half selector
    const f16v zf16 = {0.f,0.f,0.f,0.f,0.f,0.f,0.f,0.f,
                       0.f,0.f,0.f,0.f,0.f,0.f,0.f,0.f};

    // ---- convoy breaker: phase-stagger the 16 waves of each CU ----
    // slot 0..15; each slot ~512 cycles apart -> waves spread across one
    // tile-latency so redist/MFMA/load phases of different waves overlap.
    {
        const int slot = wv + 8 * (blockIdx.x & 1);
        for (int i = 0; i < slot; ++i) __builtin_amdgcn_s_sleep(8);
    }

    // hoist L3 weight fragments (loop-invariant)
    s8v w2f[4];
    #pragma unroll
    for (int kc = 0; kc < 4; kc++)
        w2f[kc] = *(const s8v*)(smem + OFF_W2T + l5*72 + kc*16 + hi*8);

    auto loadRow8f = [&](const void* p, int eoff) -> s8v {
        const float* f = (const float*)p + eoff;
        f4v f0 = *(const f4v*)f;
        f4v f1 = *(const f4v*)(f + 4);
        s8v r;
        #pragma unroll
        for (int j = 0; j < 4; j++) {
            r[j]     = bf2s(__float2bfloat16(f0[j]));
            r[j + 4] = bf2s(__float2bfloat16(f1[j]));
        }
        return r;
    };
    auto putOut = [&](int idx, float v) {
        if (isbf) ((short*)outp)[idx] = bf2s(__float2bfloat16(v));
        else      ((float*)outp)[idx] = v;
    };
    auto cvtpk = [](float lo, float hiV) -> unsigned int {
        unsigned int r;
        asm("v_cvt_pk_bf16_f32 %0, %1, %2" : "=v"(r) : "v"(lo), "v"(hiV));
        return r;
    };
    auto swap32 = [](unsigned int &x, unsigned int &y) {
        asm("v_permlane32_swap_b32 %0, %1" : "+v"(x), "+v"(y));
    };

    // ---- redistribution: 32x32 D acc (2 m-tiles = 64 feats) -> 4 B-frags ----
    auto redist32 = [&](const f16v &a0, const f16v &a1, s8v (&fr)[4]) {
        unsigned int Q[2][4][2];
        #pragma unroll
        for (int tt = 0; tt < 2; tt++) {
            const f16v &a = tt ? a1 : a0;
            #pragma unroll
            for (int aa = 0; aa < 4; aa++)
                #pragma unroll
                for (int e = 0; e < 2; e++)
                    Q[tt][aa][e] = cvtpk(fmaxf(a[4*aa + 2*e], 0.f),
                                         fmaxf(a[4*aa + 2*e + 1], 0.f));
        }
        #pragma unroll
        for (int tt = 0; tt < 2; tt++)
            #pragma unroll
            for (int A = 0; A < 2; A++)
                #pragma unroll
                for (int e = 0; e < 2; e++)
                    swap32(Q[tt][2*A][e], Q[tt][2*A + 1][e]);
        #pragma unroll
        for (int c = 0; c < 4; c++) {
            const int tt = c >> 1, A = c & 1;
            union { unsigned int u[4]; s8v v; } fu;
            fu.u[0] = Q[tt][2*A][0];     fu.u[1] = Q[tt][2*A][1];
            fu.u[2] = Q[tt][2*A + 1][0]; fu.u[3] = Q[tt][2*A + 1][1];
            fr[c] = fu.v;
        }
    };
    // junction: 16-feat tile (regs 0..7 hold feats 0..15) -> one B-frag
    auto redistJ = [&](const f16v &a, s8v &fg) {
        unsigned int Q[2][2];
        #pragma unroll
        for (int aa = 0; aa < 2; aa++)
            #pragma unroll
            for (int e = 0; e < 2; e++)
                Q[aa][e] = cvtpk(fmaxf(a[4*aa + 2*e], 0.f),
                                 fmaxf(a[4*aa + 2*e + 1], 0.f));
        #pragma unroll
        for (int e = 0; e < 2; e++) swap32(Q[0][e], Q[1][e]);
        union { unsigned int u[4]; s8v v; } fu;
        fu.u[0] = Q[0][0]; fu.u[1] = Q[0][1];
        fu.u[2] = Q[1][0]; fu.u[3] = Q[1][1];
        fg = fu.v;
    };

    // 64-out layer: A = W^T from LDS, B = activation frags, K=64
    auto layer64 = [&](int woff, const s8v (&b)[4], f16v (&o)[2]) {
        #pragma unroll
        for (int mt = 0; mt < 2; mt++) {
            s8v a0 = *(const s8v*)(smem + woff + (mt*32 + l5)*72 +  0 + hi*8);
            s8v a1 = *(const s8v*)(smem + woff + (mt*32 + l5)*72 + 16 + hi*8);
            s8v a2 = *(const s8v*)(smem + woff + (mt*32 + l5)*72 + 32 + hi*8);
            s8v a3 = *(const s8v*)(smem + woff + (mt*32 + l5)*72 + 48 + hi*8);
            __builtin_amdgcn_s_setprio(1);
            f16v c = zf16;
            c = MFMA32(a0, b[0], c, 0, 0, 0);
            c = MFMA32(a1, b[1], c, 0, 0, 0);
            c = MFMA32(a2, b[2], c, 0, 0, 0);
            c = MFMA32(a3, b[3], c, 0, 0, 0);
            __builtin_amdgcn_s_setprio(0);
            o[mt] = c;
        }
    };

    const int ntiles = npts / 32;
    const int nw     = gridDim.x * 8;   // 4096 waves
    int tile = blockIdx.x * 8 + wv;

    auto loadB2 = [&](const void* p, int r0, s8v (&f)[2]) {
        #pragma unroll
        for (int kc = 0; kc < 2; kc++) {
            const int off = (r0 + l5)*32 + kc*16 + hi*8;
            f[kc] = isbf ? *(const s8v*)((const short*)p + off) : loadRow8f(p, off);
        }
    };

    // prologue: current tile's x AND d
    s8v xb[2], db[2];
    if (tile < ntiles) { loadB2(xv, tile*32, xb); loadB2(dv, tile*32, db); }

    #pragma unroll 1
    for (; tile < ntiles; tile += nw) {
        const int r0   = tile * 32;
        const int nxt  = tile + nw;
        const int nclp = (nxt < ntiles) ? nxt : tile;   // clamped prefetch addr

        // ---------------- sigma net ----------------
        // L1: H1^T(64x32) = Ws0^T @ X^T, K=32
        f16v h[2];
        #pragma unroll
        for (int mt = 0; mt < 2; mt++) {
            s8v a0 = *(const s8v*)(smem + OFF_W0T + (mt*32 + l5)*40 +  0 + hi*8);
            s8v a1 = *(const s8v*)(smem + OFF_W0T + (mt*32 + l5)*40 + 16 + hi*8);
            __builtin_amdgcn_s_setprio(1);
            f16v c = zf16;
            c = MFMA32(a0, xb[0], c, 0, 0, 0);
            c = MFMA32(a1, xb[1], c, 0, 0, 0);
            __builtin_amdgcn_s_setprio(0);
            h[mt] = c;
        }

        // xb consumed: prefetch next tile's x (hides under L2..C3)
        s8v xbn[2];
        loadB2(xv, nclp*32, xbn);

        s8v bfr[4];
        redist32(h[0], h[1], bfr);

        // L2
        layer64(OFF_W1T, bfr, h);
        redist32(h[0], h[1], bfr);

        // L3: 16 real out-feats (rows 16..31 of A are zero)
        __builtin_amdgcn_s_setprio(1);
        f16v s3 = zf16;
        #pragma unroll
        for (int kc = 0; kc < 4; kc++)
            s3 = MFMA32(w2f[kc], bfr[kc], s3, 0, 0, 0);
        __builtin_amdgcn_s_setprio(0);

        // sigma = relu(feat 0): reg 0 at lanes hi==0, point = l5
        if (hi == 0) putOut(3*npts + r0 + l5, fmaxf(s3[0], 0.f));

        // junction: geo feats into the k in [32,48) B-frag (k=32 row is zero)
        s8v geo;
        redistJ(s3, geo);

        // ---------------- color net ----------------
        // C0: k<32 = d, k in [32,48) = geo, k>=48 zero rows (skipped)
        #pragma unroll
        for (int mt = 0; mt < 2; mt++) {
            const int base = OFF_WC0T + (mt*32 + l5)*72;
            s8v a0 = *(const s8v*)(smem + base +  0 + hi*8);
            s8v a1 = *(const s8v*)(smem + base + 16 + hi*8);
            s8v a2 = *(const s8v*)(smem + base + 32 + hi*8);
            __builtin_amdgcn_s_setprio(1);
            f16v c = zf16;
            c = MFMA32(a0, db[0], c, 0, 0, 0);
            c = MFMA32(a1, db[1], c, 0, 0, 0);
            c = MFMA32(a2, geo,   c, 0, 0, 0);
            __builtin_amdgcn_s_setprio(0);
            h[mt] = c;
        }

        // db consumed: prefetch next tile's d (hides under C1..C3 + next sigma)
        s8v dbn[2];
        loadB2(dv, nclp*32, dbn);

        redist32(h[0], h[1], bfr);

        // C1
        layer64(OFF_WC1T, bfr, h);
        redist32(h[0], h[1], bfr);

        // C2
        layer64(OFF_WC2T, bfr, h);
        redist32(h[0], h[1], bfr);

        // C3: rgb = rows 0..2 (rows 3..31 of A zero)
        __builtin_amdgcn_s_setprio(1);
        f16v c7 = zf16;
        #pragma unroll
        for (int kc = 0; kc < 4; kc++) {
            s8v a = *(const s8v*)(smem + OFF_WC3T + l5*72 + kc*16 + hi*8);
            c7 = MFMA32(a, bfr[kc], c7, 0, 0, 0);
        }
        __builtin_amdgcn_s_setprio(0);
        if (hi == 0) {
            const int base = (r0 + l5) * 3;
            #pragma unroll
            for (int r = 0; r < 3; r++) {
                float sg = 1.0f / (1.0f + __expf(-c7[r]));
                putOut(base + r, sg);
            }
        }

        xb[0] = xbn[0]; xb[1] = xbn[1];
        db[0] = dbn[0]; db[1] = dbn[1];
    }
}

extern "C" void kernel_launch(void* const* d_in, const int* in_sizes, int n_in,
                              void* d_out, int out_size, void* d_ws, size_t ws_size,
                              hipStream_t stream) {
    const int npts = in_sizes[0] / 32;
    // 512 blocks x 512 thr; 51.2 KB LDS -> 2 blocks/CU, 16 waves/CU.
    // Waves phase-staggered ~512cyc apart; setprio(1) wraps MFMA clusters.
    rf_fused<<<512, 512, 0, stream>>>(d_in[0], d_in[1], d_in[2], d_in[3], d_in[4],
                                      d_in[5], d_in[6], d_in[7], d_in[8],
                                      d_out, npts);
}